// Round 1
// baseline (306.734 us; speedup 1.0000x reference)
//
#include <hip/hip_runtime.h>

// InstantNGP hash-grid encoding, fp32.
// N_POINTS=1048576, N_LEVELS=16, F=2, BASE_RES=16, FINEST_RES=512.
// SIZES[l] = 2^(l+1), OFFS[l] = 2^(l+1)-2  (closed form, no tables).
// Hash: ((x*P1 + y)*P2 + z)*P3 mod 2^32 = x*(P1*P2*P3) + y*(P2*P3) + z*P3.

#define N_POINTS 1048576
#define N_LEVELS 16

__global__ __launch_bounds__(256) void ngp_encode_kernel(
    const float* __restrict__ coords,
    const float* __restrict__ table,
    float* __restrict__ out)
{
    const int i = blockIdx.x * blockDim.x + threadIdx.x;
    if (i >= N_POINTS) return;

    const float px = coords[3 * i + 0];
    const float py = coords[3 * i + 1];
    const float pz = coords[3 * i + 2];

    constexpr unsigned P1 = 2654435761u, P2 = 29675113u, P3 = 123456789u;
    constexpr unsigned HA = P1 * P2 * P3;  // x coefficient (mod 2^32)
    constexpr unsigned HB = P2 * P3;       // y coefficient
    constexpr unsigned HC = P3;            // z coefficient

    const float2* __restrict__ tb = (const float2*)table;

    float res_out[2 * N_LEVELS];

#pragma unroll
    for (int l = 0; l < N_LEVELS; ++l) {
        int res_i = 16 << l;
        if (res_i > 512) res_i = 512;
        const float fres = (float)res_i;

        const float csx = (px + 1.0f) * fres;
        const float csy = (py + 1.0f) * fres;
        const float csz = (pz + 1.0f) * fres;
        const float cfx = floorf(csx);
        const float cfy = floorf(csy);
        const float cfz = floorf(csz);
        const float tx = csx - cfx;
        const float ty = csy - cfy;
        const float tz = csz - cfz;
        const unsigned bx = (unsigned)cfx;
        const unsigned by = (unsigned)cfy;
        const unsigned bz = (unsigned)cfz;

        const unsigned mask = (2u << l) - 1u;
        const unsigned off  = (2u << l) - 2u;

        const unsigned h000 = bx * HA + by * HB + bz * HC;

        const float2 f000 = tb[off + ((h000) & mask)];
        const float2 f100 = tb[off + ((h000 + HA) & mask)];
        const float2 f010 = tb[off + ((h000 + HB) & mask)];
        const float2 f110 = tb[off + ((h000 + HA + HB) & mask)];
        const float2 f001 = tb[off + ((h000 + HC) & mask)];
        const float2 f101 = tb[off + ((h000 + HA + HC) & mask)];
        const float2 f011 = tb[off + ((h000 + HB + HC) & mask)];
        const float2 f111 = tb[off + ((h000 + HA + HB + HC) & mask)];

        // Weighted-sum trilinear, matching reference op order.
        const float ux = 1.0f - tx, uy = 1.0f - ty, uz = 1.0f - tz;
        const float w000 = ux * uy * uz;
        const float w100 = tx * uy * uz;
        const float w010 = ux * ty * uz;
        const float w110 = tx * ty * uz;
        const float w001 = ux * uy * tz;
        const float w101 = tx * uy * tz;
        const float w011 = ux * ty * tz;
        const float w111 = tx * ty * tz;

        float o0 = f000.x * w000 + f100.x * w100 + f010.x * w010 + f110.x * w110
                 + f001.x * w001 + f101.x * w101 + f011.x * w011 + f111.x * w111;
        float o1 = f000.y * w000 + f100.y * w100 + f010.y * w010 + f110.y * w110
                 + f001.y * w001 + f101.y * w101 + f011.y * w011 + f111.y * w111;

        res_out[2 * l + 0] = o0;
        res_out[2 * l + 1] = o1;
    }

    // Each thread owns a contiguous 128 B output row: write as 8 x float4.
    float4* __restrict__ o4 = (float4*)(out + (size_t)i * 32);
#pragma unroll
    for (int k = 0; k < 8; ++k) {
        o4[k] = make_float4(res_out[4 * k + 0], res_out[4 * k + 1],
                            res_out[4 * k + 2], res_out[4 * k + 3]);
    }
}

extern "C" void kernel_launch(void* const* d_in, const int* in_sizes, int n_in,
                              void* d_out, int out_size, void* d_ws, size_t ws_size,
                              hipStream_t stream) {
    const float* coords = (const float*)d_in[0];
    const float* table  = (const float*)d_in[1];
    float* out = (float*)d_out;

    const int block = 256;
    const int grid = (N_POINTS + block - 1) / block;
    ngp_encode_kernel<<<grid, block, 0, stream>>>(coords, table, out);
}

// Round 2
// 248.920 us; speedup vs baseline: 1.2323x; 1.2323x over previous
//
#include <hip/hip_runtime.h>

// InstantNGP hash-grid encoding, fp32.
// N_POINTS=1048576, N_LEVELS=16, F=2, BASE_RES=16, FINEST_RES=512.
// SIZES[l] = 2^(l+1), OFFS[l] = 2^(l+1)-2  (closed form).
// Hash: ((x*P1 + y)*P2 + z)*P3 mod 2^32 = x*(P1*P2*P3) + y*(P2*P3) + z*P3.
//
// R1 analysis: kernel is bound by divergent-gather issue rate (~1 distinct
// 64B line/cycle/CU), not HBM (10%) or VALU (9%). Fix: levels 0..12 occupy
// the FIRST 16382 contiguous rows (128 KB) of the table -> stage them in LDS
// once per block and gather via ds_read_b64. Only levels 13..15 stay global.
// 1024-thread blocks keep 16 waves/CU despite 128 KB LDS (same occupancy as
// the 256-thread baseline measured at 49%).

#define N_POINTS 1048576
#define N_LEVELS 16
#define BLOCK 1024
#define STAGED_ROWS 16382                 // levels 0..12 = 2^14 - 2 rows
#define STAGED_BYTES (STAGED_ROWS * 8)    // 131056 B (8191 float4)

__global__ __launch_bounds__(BLOCK) void ngp_encode_kernel(
    const float* __restrict__ coords,
    const float* __restrict__ table,
    float* __restrict__ out)
{
    extern __shared__ float2 lds_tb[];    // STAGED_ROWS float2 rows

    // ---- stage levels 0..12 (contiguous prefix of table) into LDS ----
    {
        float4* __restrict__ l4 = (float4*)lds_tb;
        const float4* __restrict__ t4 = (const float4*)table;
        const int n4 = STAGED_BYTES / 16;          // 8191
        for (int idx = threadIdx.x; idx < n4; idx += BLOCK)
            l4[idx] = t4[idx];
    }
    __syncthreads();

    const int i = blockIdx.x * BLOCK + threadIdx.x;

    const float px = coords[3 * i + 0];
    const float py = coords[3 * i + 1];
    const float pz = coords[3 * i + 2];

    constexpr unsigned P1 = 2654435761u, P2 = 29675113u, P3 = 123456789u;
    constexpr unsigned HA = P1 * P2 * P3;  // x coefficient (mod 2^32)
    constexpr unsigned HB = P2 * P3;       // y coefficient
    constexpr unsigned HC = P3;            // z coefficient

    const float2* __restrict__ tb = (const float2*)table;

    float res_out[2 * N_LEVELS];

#pragma unroll
    for (int l = 0; l < N_LEVELS; ++l) {
        int res_i = 16 << l;
        if (res_i > 512) res_i = 512;
        const float fres = (float)res_i;

        const float csx = (px + 1.0f) * fres;
        const float csy = (py + 1.0f) * fres;
        const float csz = (pz + 1.0f) * fres;
        const float cfx = floorf(csx);
        const float cfy = floorf(csy);
        const float cfz = floorf(csz);
        const float tx = csx - cfx;
        const float ty = csy - cfy;
        const float tz = csz - cfz;
        const unsigned bx = (unsigned)cfx;
        const unsigned by = (unsigned)cfy;
        const unsigned bz = (unsigned)cfz;

        const unsigned mask = (2u << l) - 1u;
        const unsigned off  = (2u << l) - 2u;

        const unsigned h000 = bx * HA + by * HB + bz * HC;

        float2 f000, f100, f010, f110, f001, f101, f011, f111;
        if (l <= 12) {
            // LDS gather (staged prefix; global row index == LDS row index)
            f000 = lds_tb[off + ((h000) & mask)];
            f100 = lds_tb[off + ((h000 + HA) & mask)];
            f010 = lds_tb[off + ((h000 + HB) & mask)];
            f110 = lds_tb[off + ((h000 + HA + HB) & mask)];
            f001 = lds_tb[off + ((h000 + HC) & mask)];
            f101 = lds_tb[off + ((h000 + HA + HC) & mask)];
            f011 = lds_tb[off + ((h000 + HB + HC) & mask)];
            f111 = lds_tb[off + ((h000 + HA + HB + HC) & mask)];
        } else {
            f000 = tb[off + ((h000) & mask)];
            f100 = tb[off + ((h000 + HA) & mask)];
            f010 = tb[off + ((h000 + HB) & mask)];
            f110 = tb[off + ((h000 + HA + HB) & mask)];
            f001 = tb[off + ((h000 + HC) & mask)];
            f101 = tb[off + ((h000 + HA + HC) & mask)];
            f011 = tb[off + ((h000 + HB + HC) & mask)];
            f111 = tb[off + ((h000 + HA + HB + HC) & mask)];
        }

        const float ux = 1.0f - tx, uy = 1.0f - ty, uz = 1.0f - tz;
        const float w000 = ux * uy * uz;
        const float w100 = tx * uy * uz;
        const float w010 = ux * ty * uz;
        const float w110 = tx * ty * uz;
        const float w001 = ux * uy * tz;
        const float w101 = tx * uy * tz;
        const float w011 = ux * ty * tz;
        const float w111 = tx * ty * tz;

        float o0 = f000.x * w000 + f100.x * w100 + f010.x * w010 + f110.x * w110
                 + f001.x * w001 + f101.x * w101 + f011.x * w011 + f111.x * w111;
        float o1 = f000.y * w000 + f100.y * w100 + f010.y * w010 + f110.y * w110
                 + f001.y * w001 + f101.y * w101 + f011.y * w011 + f111.y * w111;

        res_out[2 * l + 0] = o0;
        res_out[2 * l + 1] = o1;
    }

    // Contiguous 128 B output row per thread: 8 x float4 stores.
    float4* __restrict__ o4 = (float4*)(out + (size_t)i * 32);
#pragma unroll
    for (int k = 0; k < 8; ++k) {
        o4[k] = make_float4(res_out[4 * k + 0], res_out[4 * k + 1],
                            res_out[4 * k + 2], res_out[4 * k + 3]);
    }
}

extern "C" void kernel_launch(void* const* d_in, const int* in_sizes, int n_in,
                              void* d_out, int out_size, void* d_ws, size_t ws_size,
                              hipStream_t stream) {
    const float* coords = (const float*)d_in[0];
    const float* table  = (const float*)d_in[1];
    float* out = (float*)d_out;

    // Allow >64 KB dynamic LDS (idempotent; safe under graph capture).
    hipFuncSetAttribute((const void*)ngp_encode_kernel,
                        hipFuncAttributeMaxDynamicSharedMemorySize,
                        STAGED_BYTES);

    const int grid = N_POINTS / BLOCK;
    ngp_encode_kernel<<<grid, BLOCK, STAGED_BYTES, stream>>>(coords, table, out);
}